// Round 6
// baseline (864.290 us; speedup 1.0000x reference)
//
#include <hip/hip_runtime.h>
#include <hip/hip_bf16.h>
#include <math.h>

// ---------------------------------------------------------------------------
// Mamba2 mixer forward, MI355X. Round 6: SSM mid-pipeline overhaul.
// R5: 843us (in-proj 222us @640TF). Mid-pipeline ~450us is now dominant.
//  - y_ssm_k: fused Y_off + Y_diag + D*x, single yb write (-128MB RMW).
//    LDS: SIt[128][68]f32 + acs + union{Ct[64][128]u16 | xsT bf16 + Mt f32}
//    = 61.4KB. xsT bf16 (error damped by RMSNorm downstream).
//  - G GEMM -> batched gemm_dma_k (bf16 convx inputs, fp32 out, MFMA).
//  - recur_k split 4x (512 blocks).
// ---------------------------------------------------------------------------

#define B_SZ 2
#define L_SZ 2048
#define H_SZ 2048
#define I_SZ 4096
#define N_SZ 128
#define NH_SZ 64
#define P_SZ 64
#define CH_SZ 256
#define NC_SZ 8
#define PROJ_SZ 8512
#define CONV_SZ 4352
#define XOFF 4096   // xBC start inside proj row
#define DTOFF 8448  // dt start inside proj row
#define BOFF 4096   // B start inside convx row
#define COFF 4224   // C start inside convx row

typedef __attribute__((ext_vector_type(8))) short short8_t;   // 8 bf16 frag
typedef __attribute__((ext_vector_type(4))) float float4_t;   // MFMA acc

// Direct-to-LDS DMA, 16 B per lane, wave-uniform LDS base.
#define GLDS(gp, lp)                                                   \
  __builtin_amdgcn_global_load_lds(                                    \
      (const __attribute__((address_space(1))) void*)(gp),             \
      (__attribute__((address_space(3))) void*)(lp), 16, 0, 0)

__device__ __forceinline__ float bf2f(unsigned short u) {
  union { unsigned int i; float f; } v; v.i = ((unsigned int)u) << 16; return v.f;
}
__device__ __forceinline__ unsigned short f2bf(float f) {
  union { float f; unsigned int i; } v; v.f = f;
  unsigned int b = v.i + 0x7fffu + ((v.i >> 16) & 1u);
  return (unsigned short)(b >> 16);
}
__device__ __forceinline__ void unpack8(uint4 v, float* f) {
  f[0] = bf2f((unsigned short)(v.x & 0xffffu)); f[1] = bf2f((unsigned short)(v.x >> 16));
  f[2] = bf2f((unsigned short)(v.y & 0xffffu)); f[3] = bf2f((unsigned short)(v.y >> 16));
  f[4] = bf2f((unsigned short)(v.z & 0xffffu)); f[5] = bf2f((unsigned short)(v.z >> 16));
  f[6] = bf2f((unsigned short)(v.w & 0xffffu)); f[7] = bf2f((unsigned short)(v.w >> 16));
}
__device__ __forceinline__ float silu_f(float x) { return x / (1.f + expf(-x)); }

__device__ __forceinline__ float load1(const void* p, long long e, int fp32) {
  return fp32 ? ((const float*)p)[e] : bf2f(((const unsigned short*)p)[e]);
}
__device__ __forceinline__ void load4(const void* p, long long e, int fp32, float* f) {
  if (fp32) {
    float4 a = *(const float4*)((const float*)p + e);
    f[0] = a.x; f[1] = a.y; f[2] = a.z; f[3] = a.w;
  } else {
    uint2 v = *(const uint2*)((const unsigned short*)p + e);
    f[0] = bf2f((unsigned short)(v.x & 0xffffu)); f[1] = bf2f((unsigned short)(v.x >> 16));
    f[2] = bf2f((unsigned short)(v.y & 0xffffu)); f[3] = bf2f((unsigned short)(v.y >> 16));
  }
}
__device__ __forceinline__ void load8(const void* p, long long e, int fp32, float* f) {
  if (fp32) {
    float4 a = *(const float4*)((const float*)p + e);
    float4 b = *(const float4*)((const float*)p + e + 4);
    f[0] = a.x; f[1] = a.y; f[2] = a.z; f[3] = a.w;
    f[4] = b.x; f[5] = b.y; f[6] = b.z; f[7] = b.w;
  } else {
    uint4 v = *(const uint4*)((const unsigned short*)p + e);
    unpack8(v, f);
  }
}

// ---------------------------------------------------------------------------
// Per-tensor dtype detector (confirmed working R3-R5).
// ---------------------------------------------------------------------------
__global__ void detect_k(const void* p0, const void* p1, const void* p2,
                         const void* p3, const void* p4, const void* p5,
                         const void* p6, const void* p7, const void* p8,
                         int n0, int n1, int n2, int n3, int n4, int n5,
                         int n6, int n7, int n8, int* flags) {
  __shared__ int pe, po;
  const void* ps[9] = {p0, p1, p2, p3, p4, p5, p6, p7, p8};
  int ns[9] = {n0, n1, n2, n3, n4, n5, n6, n7, n8};
  int t = threadIdx.x;
  for (int i = 0; i < 9; i++) {
    if (t == 0) { pe = 0; po = 0; }
    __syncthreads();
    int S = ns[i] < 256 ? ns[i] : 256;
    if (t < S) {
      unsigned short u = ((const unsigned short*)ps[i])[t];
      int ex = (u >> 7) & 0xFF;
      int plaus = ((u & 0x7FFFu) != 0) && (ex >= 0x70) && (ex <= 0x8F);
      if (plaus) { if (t & 1) atomicAdd(&po, 1); else atomicAdd(&pe, 1); }
    }
    __syncthreads();
    if (t == 0) flags[i] = (2 * pe < po) ? 1 : 0;
    __syncthreads();
  }
  if (t == 0) { flags[14] = 0; flags[15] = 0; }  // internal buffers: bf16
}

// ---------------------------------------------------------------------------
// fp32 (or bf16 passthrough) -> packed bf16. 8 elems/thread.
// ---------------------------------------------------------------------------
__global__ __launch_bounds__(256)
void cvt_bf16_k(const void* __restrict__ src, unsigned short* __restrict__ dst,
                long long n8, const int* __restrict__ flags, int fi) {
  long long g = (long long)blockIdx.x * 256 + threadIdx.x;
  if (g >= n8) return;
  long long e = g * 8;
  if (flags[fi]) {
    const float* s = (const float*)src + e;
    float4 a = *(const float4*)s;
    float4 b = *(const float4*)(s + 4);
    unsigned short o[8] = {f2bf(a.x), f2bf(a.y), f2bf(a.z), f2bf(a.w),
                           f2bf(b.x), f2bf(b.y), f2bf(b.z), f2bf(b.w)};
    *(uint4*)(dst + e) = *(const uint4*)o;
  } else {
    *(uint4*)(dst + e) = *(const uint4*)((const unsigned short*)src + e);
  }
}

// ---------------------------------------------------------------------------
// DMA MFMA GEMM (batched): C[z][M,N] = A[z][M,K] @ B[z][N,K]^T, bf16 in.
// 128x128 tile, BK=32, global_load_lds width=16. OUT_MODE: 0=bf16, 1=fp32,
// 2=runtime (flags[fo]). Strides sA/sB/sC in elements per z.
// ---------------------------------------------------------------------------
template <int OUT_MODE>
__global__ __launch_bounds__(256)
void gemm_dma_k(const unsigned short* __restrict__ A,
                const unsigned short* __restrict__ B,
                void* __restrict__ Cptr, int M, int N, int K,
                int lda, int ldb, int ldc,
                long long sA, long long sB, long long sC,
                const int* __restrict__ flags, int fo) {
  __shared__ unsigned short As[128 * 32];
  __shared__ unsigned short Bs[128 * 32];
  const int t = threadIdx.x;
  const int lane = t & 63;
  const int wave = t >> 6;
  const int quad = lane >> 4;
  const int l16 = lane & 15;
  const int m0 = blockIdx.y * 128, n0 = blockIdx.x * 128;
  const int wm = (wave >> 1) * 64, wn = (wave & 1) * 64;
  const int ofp = (OUT_MODE == 2) ? flags[fo] : (OUT_MODE == 1);
  const long long zoff = (long long)blockIdx.z;
  A += zoff * sA;
  B += zoff * sB;

  float4_t acc[4][4];
#pragma unroll
  for (int i = 0; i < 4; i++)
#pragma unroll
    for (int j = 0; j < 4; j++) acc[i][j] = (float4_t){0.f, 0.f, 0.f, 0.f};

  const int rr = lane >> 2;
  const int ks = (lane & 3) * 8;
  const long long aR0 = (long long)(m0 + wave * 16 + rr) * lda + ks;
  const long long aR1 = aR0 + (long long)64 * lda;
  const long long bR0 = (long long)(n0 + wave * 16 + rr) * ldb + ks;
  const long long bR1 = bR0 + (long long)64 * ldb;
  unsigned short* asd0 = &As[(wave * 16) * 32];
  unsigned short* asd1 = &As[(64 + wave * 16) * 32];
  unsigned short* bsd0 = &Bs[(wave * 16) * 32];
  unsigned short* bsd1 = &Bs[(64 + wave * 16) * 32];

  for (int k0 = 0; k0 < K; k0 += 32) {
    __syncthreads();
    GLDS(A + aR0 + k0, asd0);
    GLDS(A + aR1 + k0, asd1);
    GLDS(B + bR0 + k0, bsd0);
    GLDS(B + bR1 + k0, bsd1);
    __syncthreads();
    short8_t afr[4], bfr[4];
#pragma unroll
    for (int i = 0; i < 4; i++)
      afr[i] = *(const short8_t*)&As[(wm + i * 16 + l16) * 32 + quad * 8];
#pragma unroll
    for (int j = 0; j < 4; j++)
      bfr[j] = *(const short8_t*)&Bs[(wn + j * 16 + l16) * 32 + quad * 8];
#pragma unroll
    for (int i = 0; i < 4; i++)
#pragma unroll
      for (int j = 0; j < 4; j++)
        acc[i][j] = __builtin_amdgcn_mfma_f32_16x16x32_bf16(
            afr[i], bfr[j], acc[i][j], 0, 0, 0);
  }
#pragma unroll
  for (int i = 0; i < 4; i++) {
#pragma unroll
    for (int r = 0; r < 4; r++) {
      const int m = m0 + wm + i * 16 + quad * 4 + r;
      const long long base = zoff * sC + (long long)m * ldc;
#pragma unroll
      for (int j = 0; j < 4; j++) {
        const int n = n0 + wn + j * 16 + l16;
        if (n < N) {
          float v = acc[i][j][r];
          if (ofp) ((float*)Cptr)[base + n] = v;
          else     ((unsigned short*)Cptr)[base + n] = f2bf(v);
        }
      }
    }
  }
}

// ---------------------------------------------------------------------------
// Depthwise causal conv (K=4) + bias + SiLU over xBC columns of proj.
// ---------------------------------------------------------------------------
__global__ __launch_bounds__(256)
void conv_silu_k(const unsigned short* __restrict__ proj,
                 const void* __restrict__ cw,
                 const void* __restrict__ cb,
                 unsigned short* __restrict__ convx,
                 const int* __restrict__ flags) {
  const int total = B_SZ * L_SZ * (CONV_SZ / 4);
  int g = blockIdx.x * 256 + threadIdx.x;
  if (g >= total) return;
  const int fw = flags[2], fb = flags[3];
  int c4 = g % (CONV_SZ / 4);
  int bl = g / (CONV_SZ / 4);
  int l = bl & (L_SZ - 1);
  int ch = c4 * 4;
  float w0[8], w1[8];
  load8(cw, (long long)ch * 4, fw, w0);
  load8(cw, (long long)ch * 4 + 8, fw, w1);
  float accv[4];
  load4(cb, ch, fb, accv);
  float acc0 = accv[0], acc1 = accv[1], acc2 = accv[2], acc3 = accv[3];
  const long long rb = (long long)(bl - l);
#pragma unroll
  for (int k = 0; k < 4; k++) {
    int ls = l - 3 + k;
    if (ls < 0) continue;
    uint2 xv = *(const uint2*)(proj + (rb + ls) * PROJ_SZ + XOFF + ch);
    float x0 = bf2f((unsigned short)(xv.x & 0xffffu));
    float x1 = bf2f((unsigned short)(xv.x >> 16));
    float x2 = bf2f((unsigned short)(xv.y & 0xffffu));
    float x3 = bf2f((unsigned short)(xv.y >> 16));
    acc0 = fmaf(x0, w0[k], acc0);
    acc1 = fmaf(x1, w0[4 + k], acc1);
    acc2 = fmaf(x2, w1[k], acc2);
    acc3 = fmaf(x3, w1[4 + k], acc3);
  }
  unsigned short o0 = f2bf(silu_f(acc0));
  unsigned short o1 = f2bf(silu_f(acc1));
  unsigned short o2 = f2bf(silu_f(acc2));
  unsigned short o3 = f2bf(silu_f(acc3));
  *(uint2*)(convx + (long long)bl * CONV_SZ + ch) =
      make_uint2((unsigned int)o0 | ((unsigned int)o1 << 16),
                 (unsigned int)o2 | ((unsigned int)o3 << 16));
}

// ---------------------------------------------------------------------------
__global__ __launch_bounds__(256)
void dt_prep_k(const unsigned short* __restrict__ proj,
               const void* __restrict__ dt_bias,
               float* __restrict__ dtv, const int* __restrict__ flags) {
  int g = blockIdx.x * 256 + threadIdx.x;
  int h = g & 63;
  long long bl = g >> 6;
  float v = bf2f(proj[bl * PROJ_SZ + DTOFF + h]) + load1(dt_bias, h, flags[4]);
  float sp = (v > 20.f) ? v : log1pf(expf(v));
  dtv[g] = sp;
}

// ---------------------------------------------------------------------------
__global__ __launch_bounds__(256)
void acs_scan_k(const float* __restrict__ dtv,
                const void* __restrict__ A_log,
                float* __restrict__ acs, const int* __restrict__ flags) {
  __shared__ float sd[256];
  int blk = blockIdx.x;
  int h = blk & 63;
  int bc = blk >> 6;
  int l = threadIdx.x;
  float Ah = -expf(load1(A_log, h, flags[5]));
  long long row = (long long)bc * CH_SZ + l;
  sd[l] = Ah * dtv[row * NH_SZ + h];
  for (int off = 1; off < 256; off <<= 1) {
    __syncthreads();
    float tv = (l >= off) ? sd[l - off] : 0.f;
    __syncthreads();
    sd[l] += tv;
  }
  acs[(long long)blk * CH_SZ + l] = sd[l];
}

// ---------------------------------------------------------------------------
__global__ __launch_bounds__(256)
void chunk_states_k(const unsigned short* __restrict__ convx,
                    const float* __restrict__ dtv,
                    const float* __restrict__ acs,
                    float* __restrict__ stc) {
  __shared__ float Bw[32][128];
  __shared__ float xw[32][64];
  int blk = blockIdx.x;
  int h = blk & 63;
  int bc = blk >> 6;
  int t = threadIdx.x;
  const int p0 = (t & 15) * 4, n0 = (t >> 4) * 8;
  const float* acsb = acs + (long long)blk * 256;
  const float alast = acsb[255];
  float acc[4][8];
#pragma unroll
  for (int i = 0; i < 4; i++)
#pragma unroll
    for (int j = 0; j < 8; j++) acc[i][j] = 0.f;
  const long long row0 = (long long)bc * 256;

  for (int lt0 = 0; lt0 < 256; lt0 += 32) {
    __syncthreads();
#pragma unroll
    for (int q = 0; q < 4; q++) {
      int idx4 = (t + 256 * q) * 4;
      int r = idx4 >> 7, n = idx4 & 127;
      uint2 v = *(const uint2*)(convx + (row0 + lt0 + r) * CONV_SZ + BOFF + n);
      Bw[r][n]     = bf2f((unsigned short)(v.x & 0xffffu));
      Bw[r][n + 1] = bf2f((unsigned short)(v.x >> 16));
      Bw[r][n + 2] = bf2f((unsigned short)(v.y & 0xffffu));
      Bw[r][n + 3] = bf2f((unsigned short)(v.y >> 16));
    }
#pragma unroll
    for (int q = 0; q < 2; q++) {
      int idx4 = (t + 256 * q) * 4;
      int r = idx4 >> 6, p = idx4 & 63;
      long long lg = row0 + lt0 + r;
      float sc = dtv[lg * NH_SZ + h] * expf(alast - acsb[lt0 + r]);
      uint2 v = *(const uint2*)(convx + lg * CONV_SZ + h * 64 + p);
      xw[r][p]     = bf2f((unsigned short)(v.x & 0xffffu)) * sc;
      xw[r][p + 1] = bf2f((unsigned short)(v.x >> 16)) * sc;
      xw[r][p + 2] = bf2f((unsigned short)(v.y & 0xffffu)) * sc;
      xw[r][p + 3] = bf2f((unsigned short)(v.y >> 16)) * sc;
    }
    __syncthreads();
#pragma unroll 4
    for (int lt = 0; lt < 32; lt++) {
      float4 xv = *(const float4*)&xw[lt][p0];
      float4 b0 = *(const float4*)&Bw[lt][n0];
      float4 b1 = *(const float4*)&Bw[lt][n0 + 4];
      float xa[4] = {xv.x, xv.y, xv.z, xv.w};
      float ba[8] = {b0.x, b0.y, b0.z, b0.w, b1.x, b1.y, b1.z, b1.w};
#pragma unroll
      for (int i = 0; i < 4; i++)
#pragma unroll
        for (int j = 0; j < 8; j++) acc[i][j] = fmaf(xa[i], ba[j], acc[i][j]);
    }
  }
  float* outb = stc + (long long)blk * 8192;
#pragma unroll
  for (int i = 0; i < 4; i++) {
    *(float4*)&outb[(p0 + i) * 128 + n0] =
        make_float4(acc[i][0], acc[i][1], acc[i][2], acc[i][3]);
    *(float4*)&outb[(p0 + i) * 128 + n0 + 4] =
        make_float4(acc[i][4], acc[i][5], acc[i][6], acc[i][7]);
  }
}

// ---------------------------------------------------------------------------
// Inter-chunk recurrence, in-place, split 4x for occupancy (512 blocks).
// ---------------------------------------------------------------------------
__global__ __launch_bounds__(256)
void recur_k(float* __restrict__ stc, const float* __restrict__ acs) {
  int blk = blockIdx.x;
  int part = blk & 3, bh = blk >> 2;
  int b = bh >> 6, h = bh & 63;
  int t = threadIdx.x;
  float S[8];
#pragma unroll
  for (int j = 0; j < 8; j++) S[j] = 0.f;
  for (int z = 0; z < 8; z++) {
    long long bz = ((long long)b * 8 + z) * 64 + h;
    long long base = bz * 8192;
    float e = expf(acs[bz * 256 + 255]);
#pragma unroll
    for (int j = 0; j < 8; j++) {
      int idx = (part * 8 + j) * 256 + t;
      float cs = stc[base + idx];
      stc[base + idx] = S[j];
      S[j] = fmaf(e, S[j], cs);
    }
  }
}

// ---------------------------------------------------------------------------
// Fused Y = exp(acs)*(C @ SI) + (tril(G*decay) @ x*dt) + D*x, one yb write.
// blk = ((b*8+c)*64+h). LDS 61.4KB: SIt + acs + union{Ct | xsT(bf16)+Mt}.
// ---------------------------------------------------------------------------
__global__ __launch_bounds__(256)
void y_ssm_k(const unsigned short* __restrict__ convx,
             const float* __restrict__ dtv,
             const float* __restrict__ acs,
             const float* __restrict__ Gmat,
             const float* __restrict__ sti,
             const void* __restrict__ Dw,
             float* __restrict__ y, const int* __restrict__ flags) {
  __shared__ float SIt[128][68];     // [n][p], 34816 B
  __shared__ float acs_s[256];       // 1024 B
  __shared__ float scratch_f[6400];  // 25600 B union
  unsigned short* Ct  = (unsigned short*)scratch_f;          // [64][128] u16
  unsigned short* xsT = (unsigned short*)scratch_f;          // [64] stride 68, bf16
  float* Mt = (float*)((char*)scratch_f + 8704);             // [64] stride 66, f32
  int blk = blockIdx.x;
  int h = blk & 63;
  int bc = blk >> 6;
  int t = threadIdx.x;
  const int txp = t & 15, lq = t >> 4;
  const float Dh = load1(Dw, h, flags[6]);
  const float* sib = sti + (long long)blk * 8192;
  const float* acsb = acs + (long long)blk * 256;
  const float* Gb = Gmat + (long long)bc * 65536;
  const long long row0 = (long long)bc * 256;
  acs_s[t] = acsb[t];
#pragma unroll 4
  for (int q = 0; q < 32; q++) {
    int idx = t + 256 * q;                     // sib is [p][n]
    SIt[idx & 127][idx >> 7] = sib[idx];       // -> SIt[n][p]
  }
  for (int ltile = 0; ltile < 4; ltile++) {
    __syncthreads();  // prior scratch reads done (and initial staging visible)
    // ---- stage C tile for this ltile
#pragma unroll 4
    for (int q = 0; q < 32; q++) {
      int idx = t + 256 * q;
      int lr = idx >> 7, n = idx & 127;
      Ct[lr * 128 + n] = convx[(row0 + ltile * 64 + lr) * CONV_SZ + COFF + n];
    }
    __syncthreads();
    float acc[4][4] = {};
    // ---- Y_off: sum_n C[l,n] * SI[n,p]
#pragma unroll 4
    for (int n = 0; n < 128; n++) {
      float4 sv = *(const float4*)&SIt[n][txp * 4];
      float c0 = bf2f(Ct[(lq * 4 + 0) * 128 + n]);
      float c1 = bf2f(Ct[(lq * 4 + 1) * 128 + n]);
      float c2 = bf2f(Ct[(lq * 4 + 2) * 128 + n]);
      float c3 = bf2f(Ct[(lq * 4 + 3) * 128 + n]);
      acc[0][0] = fmaf(c0, sv.x, acc[0][0]); acc[0][1] = fmaf(c0, sv.y, acc[0][1]);
      acc[0][2] = fmaf(c0, sv.z, acc[0][2]); acc[0][3] = fmaf(c0, sv.w, acc[0][3]);
      acc[1][0] = fmaf(c1, sv.x, acc[1][0]); acc[1][1] = fmaf(c1, sv.y, acc[1][1]);
      acc[1][2] = fmaf(c1, sv.z, acc[1][2]); acc[1][3] = fmaf(c1, sv.w, acc[1][3]);
      acc[2][0] = fmaf(c2, sv.x, acc[2][0]); acc[2][1] = fmaf(c2, sv.y, acc[2][1]);
      acc[2][2] = fmaf(c2, sv.z, acc[2][2]); acc[2][3] = fmaf(c2, sv.w, acc[2][3]);
      acc[3][0] = fmaf(c3, sv.x, acc[3][0]); acc[3][1] = fmaf(c3, sv.y, acc[3][1]);
      acc[3][2] = fmaf(c3, sv.z, acc[3][2]); acc[3][3] = fmaf(c3, sv.w, acc[3][3]);
    }
    // scale Y_off by exp(acs[l])
#pragma unroll
    for (int i = 0; i < 4; i++) {
      float ex = expf(acs_s[ltile * 64 + lq * 4 + i]);
      acc[i][0] *= ex; acc[i][1] *= ex; acc[i][2] *= ex; acc[i][3] *= ex;
    }
    // ---- Y_diag over stiles (scratch reused: barrier guards Ct readers)
    for (int stile = 0; stile <= ltile; stile++) {
      __syncthreads();
      // stage xsT = x*dt as bf16 (2 p per thread)
#pragma unroll
      for (int q = 0; q < 8; q++) {
        int idx = t + 256 * q;
        int ss = idx >> 5, pu = idx & 31;
        long long row = row0 + stile * 64 + ss;
        float dt_ = dtv[row * NH_SZ + h];
        unsigned int xv = *(const unsigned int*)(convx + row * CONV_SZ + h * 64 + pu * 2);
        unsigned short a = f2bf(bf2f((unsigned short)(xv & 0xffffu)) * dt_);
        unsigned short b = f2bf(bf2f((unsigned short)(xv >> 16)) * dt_);
        *(unsigned int*)&xsT[ss * 68 + pu * 2] = (unsigned int)a | ((unsigned int)b << 16);
      }
      // stage Mt = tril(G * exp(acs_l - acs_s))
#pragma unroll 4
      for (int q = 0; q < 16; q++) {
        int idx = t + 256 * q;
        int lr = idx >> 6, ss = idx & 63;
        int lg = ltile * 64 + lr, sg = stile * 64 + ss;
        float m = 0.f;
        if (sg <= lg) m = Gb[(long long)lg * 256 + sg] * expf(acs_s[lg] - acs_s[sg]);
        Mt[lr * 66 + ss] = m;
      }
      __syncthreads();
#pragma unroll 4
      for (int ss = 0; ss < 64; ss++) {
        uint2 xu = *(const uint2*)&xsT[ss * 68 + txp * 4];
        float x0 = bf2f((unsigned short)(xu.x & 0xffffu));
        float x1 = bf2f((unsigned short)(xu.x >> 16));
        float x2 = bf2f((unsigned short)(xu.y & 0xffffu));
        float x3 = bf2f((unsigned short)(xu.y >> 16));
        float m0 = Mt[(lq * 4 + 0) * 66 + ss];
        float m1 = Mt[(lq * 4 + 1) * 66 + ss];
        float m2 = Mt[(lq * 4 + 2) * 66 + ss];
        float m3 = Mt[(lq * 4 + 3) * 66 + ss];
        acc[0][0] = fmaf(m0, x0, acc[0][0]); acc[0][1] = fmaf(m0, x1, acc[0][1]);
        acc[0][2] = fmaf(m0, x2, acc[0][2]); acc[0][3] = fmaf(m0, x3, acc[0][3]);
        acc[1][0] = fmaf(m1, x0, acc[1][0]); acc[1][1] = fmaf(m1, x1, acc[1][1]);
        acc[1][2] = fmaf(m1, x2, acc[1][2]); acc[1][3] = fmaf(m1, x3, acc[1][3]);
        acc[2][0] = fmaf(m2, x0, acc[2][0]); acc[2][1] = fmaf(m2, x1, acc[2][1]);
        acc[2][2] = fmaf(m2, x2, acc[2][2]); acc[2][3] = fmaf(m2, x3, acc[2][3]);
        acc[3][0] = fmaf(m3, x0, acc[3][0]); acc[3][1] = fmaf(m3, x1, acc[3][1]);
        acc[3][2] = fmaf(m3, x2, acc[3][2]); acc[3][3] = fmaf(m3, x3, acc[3][3]);
      }
    }
    // ---- + D*x, single write
#pragma unroll
    for (int i = 0; i < 4; i++) {
      long long row = row0 + ltile * 64 + lq * 4 + i;
      uint2 xv = *(const uint2*)(convx + row * CONV_SZ + h * 64 + txp * 4);
      float4 o;
      o.x = acc[i][0] + Dh * bf2f((unsigned short)(xv.x & 0xffffu));
      o.y = acc[i][1] + Dh * bf2f((unsigned short)(xv.x >> 16));
      o.z = acc[i][2] + Dh * bf2f((unsigned short)(xv.y & 0xffffu));
      o.w = acc[i][3] + Dh * bf2f((unsigned short)(xv.y >> 16));
      *(float4*)&y[row * I_SZ + h * 64 + txp * 4] = o;
    }
  }
}

// ---------------------------------------------------------------------------
__global__ __launch_bounds__(256)
void norm_k(const float* __restrict__ y,
            const unsigned short* __restrict__ proj,
            const void* __restrict__ nw,
            unsigned short* __restrict__ yfb, const int* __restrict__ flags) {
  __shared__ float red[4];
  __shared__ float sc_s;
  int row = blockIdx.x;
  int t = threadIdx.x;
  const int fn = flags[7];
  const float* yr = y + (long long)row * I_SZ;
  const unsigned short* zr = proj + (long long)row * PROJ_SZ;
  float g[16];
  float ss = 0.f;
#pragma unroll
  for (int q = 0; q < 4; q++) {
    int i0 = q * 1024 + t * 4;
    float4 yv = *(const float4*)&yr[i0];
    uint2 zv = *(const uint2*)&zr[i0];
    float z0 = bf2f((unsigned short)(zv.x & 0xffffu));
    float z1 = bf2f((unsigned short)(zv.x >> 16));
    float z2 = bf2f((unsigned short)(zv.y & 0xffffu));
    float z3 = bf2f((unsigned short)(zv.y >> 16));
    float g0 = yv.x * silu_f(z0), g1 = yv.y * silu_f(z1);
    float g2 = yv.z * silu_f(z2), g3 = yv.w * silu_f(z3);
    g[q * 4 + 0] = g0; g[q * 4 + 1] = g1; g[q * 4 + 2] = g2; g[q * 4 + 3] = g3;
    ss += g0 * g0 + g1 * g1 + g2 * g2 + g3 * g3;
  }
#pragma unroll
  for (int off = 32; off > 0; off >>= 1) ss += __shfl_down(ss, off, 64);
  if ((t & 63) == 0) red[t >> 6] = ss;
  __syncthreads();
  if (t == 0) sc_s = rsqrtf((red[0] + red[1] + red[2] + red[3]) * (1.f / 4096.f) + 1e-5f);
  __syncthreads();
  float sc = sc_s;
#pragma unroll
  for (int q = 0; q < 4; q++) {
    int i0 = q * 1024 + t * 4;
    float nv[4];
    load4(nw, i0, fn, nv);
    unsigned short o0 = f2bf(g[q * 4 + 0] * sc * nv[0]);
    unsigned short o1 = f2bf(g[q * 4 + 1] * sc * nv[1]);
    unsigned short o2 = f2bf(g[q * 4 + 2] * sc * nv[2]);
    unsigned short o3 = f2bf(g[q * 4 + 3] * sc * nv[3]);
    *(uint2*)&yfb[(long long)row * I_SZ + i0] =
        make_uint2((unsigned int)o0 | ((unsigned int)o1 << 16),
                   (unsigned int)o2 | ((unsigned int)o3 << 16));
  }
}

// ---------------------------------------------------------------------------
extern "C" void kernel_launch(void* const* d_in, const int* in_sizes, int n_in,
                              void* d_out, int out_size, void* d_ws, size_t ws_size,
                              hipStream_t stream) {
  const void* hs     = d_in[0];
  const void* W_in   = d_in[1];
  const void* conv_w = d_in[2];
  const void* conv_b = d_in[3];
  const void* dt_b   = d_in[4];
  const void* A_log  = d_in[5];
  const void* Dw     = d_in[6];
  const void* nw     = d_in[7];
  const void* W_out  = d_in[8];

  char* ws = (char*)d_ws;
  size_t off = 0;
  auto alloc = [&](size_t bytes) -> void* {
    void* p = ws + off;
    off += (bytes + 255) & ~(size_t)255;
    return p;
  };
  const long long ML = (long long)B_SZ * L_SZ;  // 4096 rows
  int* flags = (int*)alloc(64);
  unsigned short* proj  = (unsigned short*)alloc(ML * PROJ_SZ * 2);             // 66.5 MB
  unsigned short* convx = (unsigned short*)alloc(ML * CONV_SZ * 2);             // 34 MB
  float* dtv  = (float*)alloc(ML * NH_SZ * 4);                                  // 1 MB
  float* acsb = (float*)alloc((long long)B_SZ * NC_SZ * NH_SZ * CH_SZ * 4);     // 1 MB
  float* Gm   = (float*)alloc((long long)B_SZ * NC_SZ * CH_SZ * CH_SZ * 4);     // 4 MB
  float* stc  = (float*)alloc((long long)B_SZ * NC_SZ * NH_SZ * P_SZ * N_SZ * 4);  // 32 MB
  float* yb   = (float*)alloc(ML * I_SZ * 4);                                   // 64 MB
  unsigned short* yfb = (unsigned short*)stc;  // alias: stc dead after y_ssm_k
  // bf16 staging copies alias yb (dead until y_ssm_k / after norm_k)
  unsigned short* hs_bf   = (unsigned short*)yb;                 // 16 MB
  unsigned short* Win_bf  = (unsigned short*)yb + 8388608;       // 34.9 MB
  unsigned short* Wout_bf = (unsigned short*)yb;                 // 16 MB (after norm_k)
  (void)n_in; (void)out_size;
  if (off > ws_size) return;

  dim3 blk(256);
  // 0. dtype detection + conversions
  detect_k<<<1, blk, 0, stream>>>(hs, W_in, conv_w, conv_b, dt_b, A_log, Dw, nw, W_out,
                                  in_sizes[0], in_sizes[1], in_sizes[2], in_sizes[3],
                                  in_sizes[4], in_sizes[5], in_sizes[6], in_sizes[7],
                                  in_sizes[8], flags);
  cvt_bf16_k<<<dim3(4096), blk, 0, stream>>>(hs, hs_bf, 1048576LL, flags, 0);
  cvt_bf16_k<<<dim3(8512), blk, 0, stream>>>(W_in, Win_bf, 2179072LL, flags, 1);
  // 1. in-proj (DMA MFMA)
  gemm_dma_k<0><<<dim3(67, 32, 1), blk, 0, stream>>>(
      hs_bf, Win_bf, proj, 4096, PROJ_SZ, H_SZ, H_SZ, H_SZ, PROJ_SZ,
      0, 0, 0, flags, 15);
  // 2-4. conv+silu, dt, cumsum
  conv_silu_k<<<dim3((B_SZ * L_SZ * (CONV_SZ / 4) + 255) / 256), blk, 0, stream>>>(
      proj, conv_w, conv_b, convx, flags);
  dt_prep_k<<<dim3((unsigned)(ML * NH_SZ / 256)), blk, 0, stream>>>(proj, dt_b, dtv, flags);
  acs_scan_k<<<dim3(B_SZ * NC_SZ * NH_SZ), blk, 0, stream>>>(dtv, A_log, acsb, flags);
  // 5. G = Cc @ Bc^T per (b,chunk) — batched DMA MFMA, fp32 out
  gemm_dma_k<1><<<dim3(2, 2, 16), blk, 0, stream>>>(
      (const unsigned short*)convx + COFF, (const unsigned short*)convx + BOFF,
      Gm, 256, 256, 128, CONV_SZ, CONV_SZ, 256,
      (long long)256 * CONV_SZ, (long long)256 * CONV_SZ, 65536, flags, 15);
  // 6. per-chunk states
  chunk_states_k<<<dim3(1024), blk, 0, stream>>>(convx, dtv, acsb, stc);
  // 7. inter-chunk recurrence (in-place, 4x split)
  recur_k<<<dim3(4 * B_SZ * NH_SZ), blk, 0, stream>>>(stc, acsb);
  // 8. fused Y_off + Y_diag + D*x
  y_ssm_k<<<dim3(1024), blk, 0, stream>>>(convx, dtv, acsb, Gm, stc, Dw, yb, flags);
  // 9. gated RMSNorm
  norm_k<<<dim3((unsigned)ML), blk, 0, stream>>>(yb, proj, nw, yfb, flags);
  // 10. out-proj (DMA MFMA); output dtype follows hs flag
  cvt_bf16_k<<<dim3(4096), blk, 0, stream>>>(W_out, Wout_bf, 1048576LL, flags, 8);
  gemm_dma_k<2><<<dim3(16, 32, 1), blk, 0, stream>>>(
      yfb, Wout_bf, d_out, 4096, H_SZ, I_SZ, I_SZ, I_SZ, H_SZ,
      0, 0, 0, flags, 0);
}